// Round 8
// baseline (244.549 us; speedup 1.0000x reference)
//
#include <hip/hip_runtime.h>
#include <hip/hip_bf16.h>

#define BB 4
#define SEQ 2048
#define NH 4
#define D 64
#define NPAIR 16
#define HOUT 8
#define LOSS_BASE ((size_t)BB * SEQ * HOUT * D)

// ---- ws layout ----
// f32: part[4][16][3][4096] | Spart[16][32][64] | lpart[2][16][2048]
// ushort: usb: 0 Khi, 1 VbfT, 2 UhT, 3 EhiT, 4 valsT, 5 Ughi, 6 Uglo  (each 16*2048*64)
// ushort: OpartUS[2][16][2048][64]
#define N_PART   (4 * 16 * 3 * 4096)
#define OFF_SPART N_PART
#define N_SPART  (16 * 32 * 64)
#define OFF_LPART (OFF_SPART + N_SPART)
#define N_LPART  (2 * 16 * 2048)
#define OFF_F32_END (OFF_LPART + N_LPART)
#define USZ ((size_t)16 * 2048 * 64)

typedef __attribute__((ext_vector_type(8))) short bf16x8;
typedef __attribute__((ext_vector_type(4))) float f32x4;
typedef __attribute__((ext_vector_type(8))) unsigned short us8;
typedef __attribute__((ext_vector_type(4))) unsigned short us4;

__device__ __forceinline__ unsigned short f2bf(float x) {
    union { float f; unsigned u; } v; v.f = x;
    unsigned r = v.u + 0x7fffu + ((v.u >> 16) & 1u);
    return (unsigned short)(r >> 16);
}
__device__ __forceinline__ float bf2f(unsigned short u) {
    union { unsigned u; float f; } v; v.u = ((unsigned)u) << 16; return v.f;
}
// packed RNE f32->bf16 pair: dst = bf16(lo) | bf16(hi)<<16  (bit-identical to f2bf)
__device__ __forceinline__ unsigned cvt_pk_bf16(float lo, float hi) {
    unsigned r;
    asm("v_cvt_pk_bf16_f32 %0, %1, %2" : "=v"(r) : "v"(lo), "v"(hi));
    return r;
}
__device__ __forceinline__ void load16(const float* p, float* v) {
    const float4* q = (const float4*)p;
    float4 a = q[0], b = q[1], c = q[2], d = q[3];
    v[0]=a.x; v[1]=a.y; v[2]=a.z; v[3]=a.w;
    v[4]=b.x; v[5]=b.y; v[6]=b.z; v[7]=b.w;
    v[8]=c.x; v[9]=c.y; v[10]=c.z; v[11]=c.w;
    v[12]=d.x; v[13]=d.y; v[14]=d.z; v[15]=d.w;
}
__device__ __forceinline__ void wr_bf16x16(unsigned short* dst, const float* v) {
    unsigned w[8];
#pragma unroll
    for (int i = 0; i < 8; i++) w[i] = cvt_pk_bf16(v[2 * i], v[2 * i + 1]);
    *(uint4*)dst = make_uint4(w[0], w[1], w[2], w[3]);
    *(uint4*)(dst + 8) = make_uint4(w[4], w[5], w[6], w[7]);
}

// ================= prep: stage-parallel conversions (z = stage) =================
__global__ __launch_bounds__(256) void prep(const float* __restrict__ U, const float* __restrict__ Sg,
                                            const float* __restrict__ Vagf, const float* __restrict__ vals,
                                            const float* __restrict__ Ksm, const float* __restrict__ Vsm,
                                            const float* __restrict__ gam,
                                            float* __restrict__ ws, unsigned short* __restrict__ usb,
                                            float* __restrict__ out) {
    int lt = blockIdx.x, p = blockIdx.y, stage = blockIdx.z;
    int b = p >> 2, h = p & 3;
    int tid = threadIdx.x;
    int r = tid >> 2;
    int c0 = (tid & 3) * 16;
    __shared__ float T[64][69];   // 69: col-read stride 69%32=5, c0 groups 16*69%32=16 -> 2-way (free)
    unsigned short* Khi   = usb;
    unsigned short* VbfT  = usb + USZ;
    unsigned short* UhT   = usb + 2 * USZ;
    unsigned short* EhiT  = usb + 3 * USZ;
    unsigned short* valsT = usb + 4 * USZ;
    unsigned short* Ughi  = usb + 5 * USZ;
    unsigned short* Uglo  = usb + 6 * USZ;
    float* Spart = ws + OFF_SPART;

    const size_t gbase = ((size_t)(b * SEQ + lt * 64 + r) * NH + h) * D + c0;
    const size_t nbase = ((size_t)(p * SEQ + lt * 64 + r)) * 64 + c0;      // [p][l][d]
    const size_t tbase = ((size_t)p * 64 + r) * 2048 + lt * 64 + c0;      // [p][d][l]
    float v[16], e[16];

    if (stage == 0) {
        // U -> row softmax -> Ug (natural hi/lo) + UhT (transposed bf16)
        load16(U + gbase, v);
        float mx = v[0];
#pragma unroll
        for (int k = 1; k < 16; k++) mx = fmaxf(mx, v[k]);
        mx = fmaxf(mx, __shfl_xor(mx, 1));
        mx = fmaxf(mx, __shfl_xor(mx, 2));
        float sm = 0.0f;
#pragma unroll
        for (int k = 0; k < 16; k++) { v[k] = __expf(v[k] - mx); sm += v[k]; }
        sm += __shfl_xor(sm, 1);
        sm += __shfl_xor(sm, 2);
        float inv = 1.0f / sm;
#pragma unroll
        for (int k = 0; k < 16; k++) { v[k] *= inv; T[r][c0 + k] = v[k]; }
        float sg[16];
        load16(Sg + gbase, sg);
        float g0 = gam[0], g1 = gam[1], g2 = gam[2], g3 = gam[3];
        us8 h0, h1, l0, l1;
#pragma unroll
        for (int k = 0; k < 16; k++) {
            float sig = 1.0f / (1.0f + __expf(-sg[k]));
            float x1 = 2.0f * sig;
            float x2 = 1.875f * sig * x1 - 0.75f;
            float x3 = 1.8666666666666667f * sig * x2 - 0.8f * x1;
            float ug = v[k] * (g0 + g1 * x1 + g2 * x2 + g3 * x3);
            unsigned short hh = f2bf(ug);
            unsigned short ll = f2bf(ug - bf2f(hh));
            if (k < 8) { h0[k] = hh; l0[k] = ll; } else { h1[k - 8] = hh; l1[k - 8] = ll; }
        }
        *(us8*)(Ughi + nbase) = h0; *(us8*)(Ughi + nbase + 8) = h1;
        *(us8*)(Uglo + nbase) = l0; *(us8*)(Uglo + nbase + 8) = l1;
        __syncthreads();
#pragma unroll
        for (int k = 0; k < 16; k++) e[k] = T[c0 + k][r];
        wr_bf16x16(UhT + tbase, e);
    } else if (stage == 1) {
        // E = exp(Vagf) -> EhiT + column sums
        load16(Vagf + gbase, v);
#pragma unroll
        for (int k = 0; k < 16; k++) T[r][c0 + k] = __expf(v[k]);
        __syncthreads();
        float ssum = 0.0f;
#pragma unroll
        for (int k = 0; k < 16; k++) { e[k] = T[c0 + k][r]; ssum += e[k]; }
        ssum += __shfl_xor(ssum, 1);
        ssum += __shfl_xor(ssum, 2);
        if ((tid & 3) == 0) Spart[(p * 32 + lt) * 64 + r] = ssum;
        wr_bf16x16(EhiT + tbase, e);
    } else if (stage == 2) {
        load16(vals + gbase, v);
#pragma unroll
        for (int k = 0; k < 16; k++) T[r][c0 + k] = v[k];
        __syncthreads();
#pragma unroll
        for (int k = 0; k < 16; k++) e[k] = T[c0 + k][r];
        wr_bf16x16(valsT + tbase, e);
    } else if (stage == 3) {
        load16(Vsm + gbase, v);
#pragma unroll
        for (int k = 0; k < 16; k++) T[r][c0 + k] = v[k];
        __syncthreads();
#pragma unroll
        for (int k = 0; k < 16; k++) e[k] = T[c0 + k][r];
        wr_bf16x16(VbfT + tbase, e);
    } else {
        load16(Ksm + gbase, v);
        wr_bf16x16(Khi + nbase, v);
        if (lt == 0 && p == 0 && tid < BB) out[LOSS_BASE + tid] = 0.0f;
    }
}

// ================= mid: gram (0..63) + flash (64..575, split-K x2) =================
// PSTR 74: stride 148 B -> b128 frag-read bank = (5*lm + 4*quad) mod 32 -> 2-way (free)
// vs PSTR 72 (stride 144 B) -> bank 4*(lm+quad) mod 32 -> 4-way conflict.
#define PSTR 74
// Q scale: 1/sqrt(64) * log2(e), so exp2(S) == exp(S/8)
#define QSC 0.18033688011112042f

__global__ __launch_bounds__(256, 2) void mid(const unsigned short* __restrict__ usb,
                                              const float* __restrict__ Q,
                                              float* __restrict__ part,
                                              unsigned short* __restrict__ OpartUS,
                                              float* __restrict__ lpart) {
    // flash: Kl(9472) + Vl(9472) + Ph(18944) = 37888 B; gram: 15360 B
    __shared__ __align__(16) unsigned char smem[37888];
    const int bid = blockIdx.x;
    const int tid = threadIdx.x;
    const int w = tid >> 6, lane = tid & 63, lm = lane & 15, quad = lane >> 4;

    if (bid >= 64) {
        // ---------------- flash: 128 qrows/block, LDS K/V, reg-cached A-frags, split-K x2 ----------------
        int fb = bid - 64;
        int qt2 = fb & 15, p = (fb >> 4) & 15, half = fb >> 8;
        int b = p >> 2, h = p & 3;
        const unsigned short* Khi  = usb;
        const unsigned short* VbfT = usb + USZ;
        unsigned short* Kl = (unsigned short*)smem;                        // [64][PSTR]
        unsigned short* Vl = Kl + 64 * PSTR;                               // [64][PSTR] (rows=d)
        unsigned short* Ph = Vl + 64 * PSTR;                               // [4w][2q][16][PSTR]
        const int srow = tid >> 2, sseg = (tid & 3) * 16;

        // Q B-frags for 2 q-subs: B[n=lm][k=quad*8+j], scale QSC, hi/lo
        bf16x8 qhi[2][2], qlo[2][2];
#pragma unroll
        for (int q = 0; q < 2; q++) {
            int row = qt2 * 128 + q * 64 + w * 16 + lm;
            const float* qp = Q + ((size_t)(b * SEQ + row) * NH + h) * D + quad * 8;
#pragma unroll
            for (int ks = 0; ks < 2; ks++) {
                float qq[8];
                float4 a0 = *(const float4*)(qp + ks * 32);
                float4 a1 = *(const float4*)(qp + ks * 32 + 4);
                qq[0]=a0.x; qq[1]=a0.y; qq[2]=a0.z; qq[3]=a0.w;
                qq[4]=a1.x; qq[5]=a1.y; qq[6]=a1.z; qq[7]=a1.w;
#pragma unroll
                for (int j = 0; j < 8; j++) {
                    float xs = qq[j] * QSC;
                    unsigned short hi = f2bf(xs);
                    qhi[q][ks][j] = (short)hi;
                    qlo[q][ks][j] = (short)f2bf(xs - bf2f(hi));
                }
            }
        }

        float rsum[2] = {0.f, 0.f};
        f32x4 o[2][4];
#pragma unroll
        for (int q = 0; q < 2; q++)
#pragma unroll
            for (int t = 0; t < 4; t++) o[q][t] = (f32x4){0.f, 0.f, 0.f, 0.f};

        for (int kt = 0; kt < 16; ++kt) {
            __syncthreads();
            {   // stage K [key][d] and V^T [d][key]
                size_t kb = ((size_t)(p * SEQ + half * 1024 + kt * 64 + srow)) * 64 + sseg;
                us8 k0 = *(const us8*)(Khi + kb);
                us8 k1 = *(const us8*)(Khi + kb + 8);
                size_t vb = ((size_t)p * 64 + srow) * 2048 + half * 1024 + kt * 64 + sseg;
                us8 v0 = *(const us8*)(VbfT + vb);
                us8 v1 = *(const us8*)(VbfT + vb + 8);
                *(us8*)&Kl[srow * PSTR + sseg] = k0; *(us8*)&Kl[srow * PSTR + sseg + 8] = k1;
                *(us8*)&Vl[srow * PSTR + sseg] = v0; *(us8*)&Vl[srow * PSTR + sseg + 8] = v1;
            }
            __syncthreads();

            // A-frags once per tile, reused by both q-subs
            bf16x8 kfr[4][2], vfr[4][2];
#pragma unroll
            for (int t = 0; t < 4; t++)
#pragma unroll
                for (int ks = 0; ks < 2; ks++) {
                    kfr[t][ks] = *(const bf16x8*)&Kl[(t * 16 + lm) * PSTR + ks * 32 + quad * 8];
                    vfr[t][ks] = *(const bf16x8*)&Vl[(t * 16 + lm) * PSTR + ks * 32 + quad * 8];
                }

#pragma unroll
            for (int q = 0; q < 2; q++) {
                unsigned short* Phq = Ph + (size_t)(w * 2 + q) * 16 * PSTR;
                // S^T: m=key, n=qrow. 2-pass Q hi/lo
                f32x4 s[4];
#pragma unroll
                for (int t = 0; t < 4; t++) s[t] = (f32x4){0.f, 0.f, 0.f, 0.f};
#pragma unroll
                for (int t = 0; t < 4; t++)
#pragma unroll
                    for (int ks = 0; ks < 2; ks++) {
                        s[t] = __builtin_amdgcn_mfma_f32_16x16x32_bf16(kfr[t][ks], qhi[q][ks], s[t], 0, 0, 0);
                        s[t] = __builtin_amdgcn_mfma_f32_16x16x32_bf16(kfr[t][ks], qlo[q][ks], s[t], 0, 0, 0);
                    }
                // p = exp2(s) (log2e folded into Q scale), pack via cvt_pk, per-wave LDS
#pragma unroll
                for (int t = 0; t < 4; t++) {
                    float e0 = exp2f(s[t][0]);
                    float e1 = exp2f(s[t][1]);
                    float e2 = exp2f(s[t][2]);
                    float e3 = exp2f(s[t][3]);
                    rsum[q] += (e0 + e1) + (e2 + e3);
                    unsigned w0 = cvt_pk_bf16(e0, e1);
                    unsigned w1 = cvt_pk_bf16(e2, e3);
                    *(uint2*)&Phq[lm * PSTR + t * 16 + quad * 4] = make_uint2(w0, w1);
                }
                // same-wave write->read ordering via lgkmcnt
                bf16x8 pf0 = *(const bf16x8*)&Phq[lm * PSTR + quad * 8];
                bf16x8 pf1 = *(const bf16x8*)&Phq[lm * PSTR + 32 + quad * 8];
#pragma unroll
                for (int dt = 0; dt < 4; dt++) {
                    o[q][dt] = __builtin_amdgcn_mfma_f32_16x16x32_bf16(vfr[dt][0], pf0, o[q][dt], 0, 0, 0);
                    o[q][dt] = __builtin_amdgcn_mfma_f32_16x16x32_bf16(vfr[dt][1], pf1, o[q][dt], 0, 0, 0);
                }
            }
        }

        // epilogue: bf16 partials + per-qrow denominator partial
#pragma unroll
        for (int q = 0; q < 2; q++) {
            float rs = rsum[q];
            rs += __shfl_xor(rs, 16);
            rs += __shfl_xor(rs, 32);
            int qrow = qt2 * 128 + q * 64 + w * 16 + lm;
            size_t ob = ((size_t)(half * 16 + p) * SEQ + qrow) * 64;
#pragma unroll
            for (int dt = 0; dt < 4; dt++) {
                unsigned w0 = cvt_pk_bf16(o[q][dt][0], o[q][dt][1]);
                unsigned w1 = cvt_pk_bf16(o[q][dt][2], o[q][dt][3]);
                *(uint2*)(OpartUS + ob + dt * 16 + quad * 4) = make_uint2(w0, w1);
            }
            if (quad == 0) lpart[(size_t)(half * 16 + p) * SEQ + qrow] = rs;
        }
    } else {
        // ---------------- gram: MFMA split-4 partials ----------------
        int split = bid >> 4, p = bid & 15;
        const unsigned short* UhT   = usb + 2 * USZ;
        const unsigned short* EhiT  = usb + 3 * USZ;
        const unsigned short* valsT = usb + 4 * USZ;
        unsigned short* Ut = (unsigned short*)smem;            // 64*40 each
        unsigned short* Eh = Ut + 64 * 40;
        unsigned short* Vt = Eh + 64 * 40;
        f32x4 su[4], sv[4], kv[4];
#pragma unroll
        for (int i = 0; i < 4; i++) { su[i] = (f32x4){0,0,0,0}; sv[i] = (f32x4){0,0,0,0}; kv[i] = (f32x4){0,0,0,0}; }
        int srow = tid >> 2;
        int sseg = (tid & 3) * 8;

        for (int step = 0; step < 16; ++step) {
            int l0 = split * 512 + step * 32;
            __syncthreads();
            size_t gb = ((size_t)p * 64 + srow) * 2048 + l0 + sseg;
            *(us8*)&Ut[srow * 40 + sseg] = *(const us8*)(UhT + gb);
            *(us8*)&Eh[srow * 40 + sseg] = *(const us8*)(EhiT + gb);
            *(us8*)&Vt[srow * 40 + sseg] = *(const us8*)(valsT + gb);
            __syncthreads();
            int ao = (w * 16 + lm) * 40 + quad * 8;
            bf16x8 au  = *(const bf16x8*)&Ut[ao];
            bf16x8 aeh = *(const bf16x8*)&Eh[ao];
#pragma unroll
            for (int nt = 0; nt < 4; nt++) {
                int bo = (nt * 16 + lm) * 40 + quad * 8;
                bf16x8 bu  = *(const bf16x8*)&Ut[bo];
                bf16x8 beh = *(const bf16x8*)&Eh[bo];
                bf16x8 bv  = *(const bf16x8*)&Vt[bo];
                su[nt] = __builtin_amdgcn_mfma_f32_16x16x32_bf16(au,  bu,  su[nt], 0, 0, 0);
                sv[nt] = __builtin_amdgcn_mfma_f32_16x16x32_bf16(aeh, beh, sv[nt], 0, 0, 0);
                kv[nt] = __builtin_amdgcn_mfma_f32_16x16x32_bf16(aeh, bv,  kv[nt], 0, 0, 0);
            }
        }
        float* dst = part + (size_t)(split * 16 + p) * 3 * 4096;
#pragma unroll
        for (int nt = 0; nt < 4; nt++)
#pragma unroll
            for (int reg = 0; reg < 4; reg++) {
                int off = (w * 16 + quad * 4 + reg) * 64 + nt * 16 + lm;
                dst[off] = su[nt][reg];
                dst[4096 + off] = sv[nt][reg];
                dst[8192 + off] = kv[nt][reg];
            }
    }
}

// ================= post: agf (0..511) + ortho x4 (512..575) + smerge (576..2623) =================
__global__ __launch_bounds__(256) void post(const float* __restrict__ part, const float* __restrict__ Spart,
                                            const unsigned short* __restrict__ usb,
                                            const unsigned short* __restrict__ OpartUS,
                                            const float* __restrict__ lpart, float* __restrict__ out) {
    const int bid = blockIdx.x;
    const int tid = threadIdx.x;
    if (bid >= 576) {
        // ---- smerge: combine 2 split-K halves, divide, write softmax heads ----
        int idx = (bid - 576) * 256 + tid;    // [p][l][16 dq]
        int p = idx >> 15;
        int rem = idx & 32767;
        int l = rem >> 4, dq = rem & 15;
        int b = p >> 2, h = p & 3;
        us4 a = *(const us4*)(OpartUS + ((size_t)p * SEQ + l) * 64 + dq * 4);
        us4 c = *(const us4*)(OpartUS + ((size_t)(16 + p) * SEQ + l) * 64 + dq * 4);
        float inv = 1.0f / (lpart[(size_t)p * SEQ + l] + lpart[(size_t)(16 + p) * SEQ + l]);
        f32x4 res;
#pragma unroll
        for (int r = 0; r < 4; r++) res[r] = (bf2f(a[r]) + bf2f(c[r])) * inv;
        *(f32x4*)(out + ((size_t)(b * SEQ + l) * HOUT + 4 + h) * D + dq * 4) = res;
        return;
    }
    const int w = tid >> 6, lane = tid & 63, lm = lane & 15, quad = lane >> 4;
    int p = (bid < 512) ? (bid >> 5) : ((bid - 512) >> 2);
    __shared__ float cis[64];
    __shared__ float red[4][64];
    __shared__ __align__(16) unsigned short KVh[64 * PSTR];
    __shared__ __align__(16) unsigned short KVl[64 * PSTR];
    {
        int d = tid & 63, grp = tid >> 6;
        float s = 0.0f;
#pragma unroll
        for (int i = 0; i < 8; i++) s += Spart[(p * 32 + grp * 8 + i) * 64 + d];
        red[grp][d] = s;
        __syncthreads();
        if (tid < 64) cis[tid] = 1.0f / (red[0][tid] + red[1][tid] + red[2][tid] + red[3][tid]);
        __syncthreads();
    }
    if (bid >= 512) {
        // ---- ortho loss for pair p, i-chunk (4 chunks per p) ----
        int chunk = (bid - 512) & 3;
        float s = 0.0f;
        for (int t = 0; t < 8; t++) {
            int idx = chunk * 2048 + t * 256 + tid;
            int g = idx >> 12, i = idx & 4095;
            float v = 0.0f;
#pragma unroll
            for (int sp = 0; sp < 4; sp++) v += part[((size_t)(sp * 16 + p) * 3 + g) * 4096 + i];
            if (g) v *= cis[i >> 6] * cis[i & 63];
            float dg = ((i >> 6) == (i & 63)) ? 1.0f : 0.0f;
            s += fabsf(v - dg);
        }
#pragma unroll
        for (int o = 32; o > 0; o >>= 1) s += __shfl_xor(s, o);
        if ((tid & 63) == 0) red[0][(tid >> 6) * 2] = s;
        __syncthreads();
        if (tid == 0)
            atomicAdd(&out[LOSS_BASE + (p >> 2)],
                      (red[0][0] + red[0][2] + red[0][4] + red[0][6]) * (1.0f / 16384.0f));
        return;
    }
    // ---- agf: out = Ug @ KV (3-pass bf16 MFMA) ----
    int lt = bid & 31;
    int b = p >> 2, h = p & 3;
    const unsigned short* Ughi = usb + 5 * USZ;
    const unsigned short* Uglo = usb + 6 * USZ;
    for (int idx = tid; idx < 4096; idx += 256) {
        int d = idx >> 6, e = idx & 63;
        float v = 0.0f;
#pragma unroll
        for (int sp = 0; sp < 4; sp++) v += part[((size_t)(sp * 16 + p) * 3 + 2) * 4096 + idx];
        v *= cis[d];
        unsigned short hh = f2bf(v);
        KVh[e * PSTR + d] = hh;
        KVl[e * PSTR + d] = f2bf(v - bf2f(hh));
    }
    __syncthreads();
    size_t ub = ((size_t)(p * SEQ + lt * 64 + w * 16 + lm)) * 64 + quad * 8;
    bf16x8 ah[2], al[2];
#pragma unroll
    for (int ks = 0; ks < 2; ks++) {
        ah[ks] = *(const bf16x8*)(Ughi + ub + ks * 32);
        al[ks] = *(const bf16x8*)(Uglo + ub + ks * 32);
    }
    f32x4 acc[4];
#pragma unroll
    for (int nt = 0; nt < 4; nt++) acc[nt] = (f32x4){0.f, 0.f, 0.f, 0.f};
#pragma unroll
    for (int nt = 0; nt < 4; nt++)
#pragma unroll
        for (int ks = 0; ks < 2; ks++) {
            bf16x8 bh = *(const bf16x8*)&KVh[(nt * 16 + lm) * PSTR + ks * 32 + quad * 8];
            bf16x8 bl = *(const bf16x8*)&KVl[(nt * 16 + lm) * PSTR + ks * 32 + quad * 8];
            acc[nt] = __builtin_amdgcn_mfma_f32_16x16x32_bf16(ah[ks], bh, acc[nt], 0, 0, 0);
            acc[nt] = __builtin_amdgcn_mfma_f32_16x16x32_bf16(al[ks], bh, acc[nt], 0, 0, 0);
            acc[nt] = __builtin_amdgcn_mfma_f32_16x16x32_bf16(ah[ks], bl, acc[nt], 0, 0, 0);
        }
#pragma unroll
    for (int nt = 0; nt < 4; nt++)
#pragma unroll
        for (int reg = 0; reg < 4; reg++)
            out[((size_t)(b * SEQ + lt * 64 + w * 16 + quad * 4 + reg) * HOUT + h) * D + nt * 16 + lm] =
                acc[nt][reg];
}

extern "C" void kernel_launch(void* const* d_in, const int* in_sizes, int n_in,
                              void* d_out, int out_size, void* d_ws, size_t ws_size,
                              hipStream_t stream) {
    (void)in_sizes; (void)n_in; (void)out_size; (void)ws_size;
    const float* U    = (const float*)d_in[0];
    const float* Sg   = (const float*)d_in[1];
    const float* V    = (const float*)d_in[2];
    const float* vals = (const float*)d_in[3];
    const float* Qs   = (const float*)d_in[4];
    const float* Ks   = (const float*)d_in[5];
    const float* Vv   = (const float*)d_in[6];
    const float* gam  = (const float*)d_in[7];
    float* out = (float*)d_out;

    float* ws = (float*)d_ws;
    float* part  = ws;
    float* Spart = ws + OFF_SPART;
    float* lpart = ws + OFF_LPART;
    unsigned short* usb = (unsigned short*)(ws + OFF_F32_END);
    unsigned short* OpartUS = usb + 7 * USZ;

    prep<<<dim3(32, 16, 5), 256, 0, stream>>>(U, Sg, V, vals, Ks, Vv, gam, ws, usb, out);
    mid<<<576, 256, 0, stream>>>(usb, Qs, part, OpartUS, lpart);
    post<<<2624, 256, 0, stream>>>(part, Spart, usb, OpartUS, lpart, out);
}

// Round 9
// 163.263 us; speedup vs baseline: 1.4979x; 1.4979x over previous
//
#include <hip/hip_runtime.h>
#include <hip/hip_bf16.h>

#define BB 4
#define SEQ 2048
#define NH 4
#define D 64
#define NPAIR 16
#define HOUT 8
#define LOSS_BASE ((size_t)BB * SEQ * HOUT * D)

// ---- ws layout ----
// f32: part[4][16][3][4096] | Spart[16][32][64] | lpart[2][16][2048] | cis[16][64]
// ushort: usb: 0 Khi, 1 VbfT, 2 UhT, 3 EhiT, 4 valsT, 5 Ughi, 6 Uglo  (each 16*2048*64)
// ushort: OpartUS[2][16][2048][64]
#define N_PART   (4 * 16 * 3 * 4096)
#define OFF_SPART N_PART
#define N_SPART  (16 * 32 * 64)
#define OFF_LPART (OFF_SPART + N_SPART)
#define N_LPART  (2 * 16 * 2048)
#define OFF_CIS  (OFF_LPART + N_LPART)
#define N_CIS    (16 * 64)
#define OFF_F32_END (OFF_CIS + N_CIS)
#define USZ ((size_t)16 * 2048 * 64)

typedef __attribute__((ext_vector_type(8))) short bf16x8;
typedef __attribute__((ext_vector_type(4))) float f32x4;
typedef __attribute__((ext_vector_type(8))) unsigned short us8;
typedef __attribute__((ext_vector_type(4))) unsigned short us4;

__device__ __forceinline__ unsigned short f2bf(float x) {
    union { float f; unsigned u; } v; v.f = x;
    unsigned r = v.u + 0x7fffu + ((v.u >> 16) & 1u);
    return (unsigned short)(r >> 16);
}
__device__ __forceinline__ float bf2f(unsigned short u) {
    union { unsigned u; float f; } v; v.u = ((unsigned)u) << 16; return v.f;
}
// packed RNE f32->bf16 pair: dst = bf16(lo) | bf16(hi)<<16  (bit-identical to f2bf)
__device__ __forceinline__ unsigned cvt_pk_bf16(float lo, float hi) {
    unsigned r;
    asm("v_cvt_pk_bf16_f32 %0, %1, %2" : "=v"(r) : "v"(lo), "v"(hi));
    return r;
}
__device__ __forceinline__ void load16(const float* p, float* v) {
    const float4* q = (const float4*)p;
    float4 a = q[0], b = q[1], c = q[2], d = q[3];
    v[0]=a.x; v[1]=a.y; v[2]=a.z; v[3]=a.w;
    v[4]=b.x; v[5]=b.y; v[6]=b.z; v[7]=b.w;
    v[8]=c.x; v[9]=c.y; v[10]=c.z; v[11]=c.w;
    v[12]=d.x; v[13]=d.y; v[14]=d.z; v[15]=d.w;
}
__device__ __forceinline__ void wr_bf16x16(unsigned short* dst, const float* v) {
    unsigned w[8];
#pragma unroll
    for (int i = 0; i < 8; i++) w[i] = cvt_pk_bf16(v[2 * i], v[2 * i + 1]);
    *(uint4*)dst = make_uint4(w[0], w[1], w[2], w[3]);
    *(uint4*)(dst + 8) = make_uint4(w[4], w[5], w[6], w[7]);
}

// ================= prep: stage-parallel conversions (z = stage) =================
__global__ __launch_bounds__(256) void prep(const float* __restrict__ U, const float* __restrict__ Sg,
                                            const float* __restrict__ Vagf, const float* __restrict__ vals,
                                            const float* __restrict__ Ksm, const float* __restrict__ Vsm,
                                            const float* __restrict__ gam,
                                            float* __restrict__ ws, unsigned short* __restrict__ usb,
                                            float* __restrict__ out) {
    int lt = blockIdx.x, p = blockIdx.y, stage = blockIdx.z;
    int b = p >> 2, h = p & 3;
    int tid = threadIdx.x;
    int r = tid >> 2;
    int c0 = (tid & 3) * 16;
    __shared__ float T[64][69];   // 69: col-read stride 69%32=5, c0 groups 16*69%32=16 -> 2-way (free)
    unsigned short* Khi   = usb;
    unsigned short* VbfT  = usb + USZ;
    unsigned short* UhT   = usb + 2 * USZ;
    unsigned short* EhiT  = usb + 3 * USZ;
    unsigned short* valsT = usb + 4 * USZ;
    unsigned short* Ughi  = usb + 5 * USZ;
    unsigned short* Uglo  = usb + 6 * USZ;
    float* Spart = ws + OFF_SPART;

    const size_t gbase = ((size_t)(b * SEQ + lt * 64 + r) * NH + h) * D + c0;
    const size_t nbase = ((size_t)(p * SEQ + lt * 64 + r)) * 64 + c0;      // [p][l][d]
    const size_t tbase = ((size_t)p * 64 + r) * 2048 + lt * 64 + c0;      // [p][d][l]
    float v[16], e[16];

    if (stage == 0) {
        // U -> row softmax -> Ug (natural hi/lo) + UhT (transposed bf16)
        load16(U + gbase, v);
        float mx = v[0];
#pragma unroll
        for (int k = 1; k < 16; k++) mx = fmaxf(mx, v[k]);
        mx = fmaxf(mx, __shfl_xor(mx, 1));
        mx = fmaxf(mx, __shfl_xor(mx, 2));
        float sm = 0.0f;
#pragma unroll
        for (int k = 0; k < 16; k++) { v[k] = __expf(v[k] - mx); sm += v[k]; }
        sm += __shfl_xor(sm, 1);
        sm += __shfl_xor(sm, 2);
        float inv = 1.0f / sm;
#pragma unroll
        for (int k = 0; k < 16; k++) { v[k] *= inv; T[r][c0 + k] = v[k]; }
        float sg[16];
        load16(Sg + gbase, sg);
        float g0 = gam[0], g1 = gam[1], g2 = gam[2], g3 = gam[3];
        us8 h0, h1, l0, l1;
#pragma unroll
        for (int k = 0; k < 16; k++) {
            float sig = 1.0f / (1.0f + __expf(-sg[k]));
            float x1 = 2.0f * sig;
            float x2 = 1.875f * sig * x1 - 0.75f;
            float x3 = 1.8666666666666667f * sig * x2 - 0.8f * x1;
            float ug = v[k] * (g0 + g1 * x1 + g2 * x2 + g3 * x3);
            unsigned short hh = f2bf(ug);
            unsigned short ll = f2bf(ug - bf2f(hh));
            if (k < 8) { h0[k] = hh; l0[k] = ll; } else { h1[k - 8] = hh; l1[k - 8] = ll; }
        }
        *(us8*)(Ughi + nbase) = h0; *(us8*)(Ughi + nbase + 8) = h1;
        *(us8*)(Uglo + nbase) = l0; *(us8*)(Uglo + nbase + 8) = l1;
        __syncthreads();
#pragma unroll
        for (int k = 0; k < 16; k++) e[k] = T[c0 + k][r];
        wr_bf16x16(UhT + tbase, e);
    } else if (stage == 1) {
        // E = exp(Vagf) -> EhiT + column sums
        load16(Vagf + gbase, v);
#pragma unroll
        for (int k = 0; k < 16; k++) T[r][c0 + k] = __expf(v[k]);
        __syncthreads();
        float ssum = 0.0f;
#pragma unroll
        for (int k = 0; k < 16; k++) { e[k] = T[c0 + k][r]; ssum += e[k]; }
        ssum += __shfl_xor(ssum, 1);
        ssum += __shfl_xor(ssum, 2);
        if ((tid & 3) == 0) Spart[(p * 32 + lt) * 64 + r] = ssum;
        wr_bf16x16(EhiT + tbase, e);
    } else if (stage == 2) {
        load16(vals + gbase, v);
#pragma unroll
        for (int k = 0; k < 16; k++) T[r][c0 + k] = v[k];
        __syncthreads();
#pragma unroll
        for (int k = 0; k < 16; k++) e[k] = T[c0 + k][r];
        wr_bf16x16(valsT + tbase, e);
    } else if (stage == 3) {
        load16(Vsm + gbase, v);
#pragma unroll
        for (int k = 0; k < 16; k++) T[r][c0 + k] = v[k];
        __syncthreads();
#pragma unroll
        for (int k = 0; k < 16; k++) e[k] = T[c0 + k][r];
        wr_bf16x16(VbfT + tbase, e);
    } else {
        load16(Ksm + gbase, v);
        wr_bf16x16(Khi + nbase, v);
        if (lt == 0 && p == 0 && tid < BB) out[LOSS_BASE + tid] = 0.0f;
    }
}

// ================= mid: gram+cis (0..63) + flash (64..575, split-K x2) =================
#define PSTR 72
// Q scale: 1/sqrt(64) * log2(e), so exp2(S) == exp(S/8)
#define QSC 0.18033688011112042f

__global__ __launch_bounds__(256, 2) void mid(const unsigned short* __restrict__ usb,
                                              const float* __restrict__ Q,
                                              float* __restrict__ part,
                                              unsigned short* __restrict__ OpartUS,
                                              float* __restrict__ lpart) {
    __shared__ __align__(16) unsigned char smem[36864];
    const int bid = blockIdx.x;
    const int tid = threadIdx.x;
    const int w = tid >> 6, lane = tid & 63, lm = lane & 15, quad = lane >> 4;

    if (bid >= 64) {
        // ---------------- flash: 128 qrows/block, LDS K/V, reg-cached A-frags, split-K x2 ----------------
        int fb = bid - 64;
        int qt2 = fb & 15, p = (fb >> 4) & 15, half = fb >> 8;
        int b = p >> 2, h = p & 3;
        const unsigned short* Khi  = usb;
        const unsigned short* VbfT = usb + USZ;
        unsigned short* Kl = (unsigned short*)smem;                        // [64][PSTR]
        unsigned short* Vl = Kl + 64 * PSTR;                               // [64][PSTR] (rows=d)
        unsigned short* Ph = Vl + 64 * PSTR;                               // [4w][2q][16][PSTR]
        const int srow = tid >> 2, sseg = (tid & 3) * 16;

        // Q B-frags for 2 q-subs: B[n=lm][k=quad*8+j], scale QSC, hi/lo
        bf16x8 qhi[2][2], qlo[2][2];
#pragma unroll
        for (int q = 0; q < 2; q++) {
            int row = qt2 * 128 + q * 64 + w * 16 + lm;
            const float* qp = Q + ((size_t)(b * SEQ + row) * NH + h) * D + quad * 8;
#pragma unroll
            for (int ks = 0; ks < 2; ks++) {
                float qq[8];
                float4 a0 = *(const float4*)(qp + ks * 32);
                float4 a1 = *(const float4*)(qp + ks * 32 + 4);
                qq[0]=a0.x; qq[1]=a0.y; qq[2]=a0.z; qq[3]=a0.w;
                qq[4]=a1.x; qq[5]=a1.y; qq[6]=a1.z; qq[7]=a1.w;
#pragma unroll
                for (int j = 0; j < 8; j++) {
                    float xs = qq[j] * QSC;
                    unsigned short hi = f2bf(xs);
                    qhi[q][ks][j] = (short)hi;
                    qlo[q][ks][j] = (short)f2bf(xs - bf2f(hi));
                }
            }
        }

        float rsum[2] = {0.f, 0.f};
        f32x4 o[2][4];
#pragma unroll
        for (int q = 0; q < 2; q++)
#pragma unroll
            for (int t = 0; t < 4; t++) o[q][t] = (f32x4){0.f, 0.f, 0.f, 0.f};

        for (int kt = 0; kt < 16; ++kt) {
            __syncthreads();
            {   // stage K [key][d] and V^T [d][key]
                size_t kb = ((size_t)(p * SEQ + half * 1024 + kt * 64 + srow)) * 64 + sseg;
                us8 k0 = *(const us8*)(Khi + kb);
                us8 k1 = *(const us8*)(Khi + kb + 8);
                size_t vb = ((size_t)p * 64 + srow) * 2048 + half * 1024 + kt * 64 + sseg;
                us8 v0 = *(const us8*)(VbfT + vb);
                us8 v1 = *(const us8*)(VbfT + vb + 8);
                *(us8*)&Kl[srow * PSTR + sseg] = k0; *(us8*)&Kl[srow * PSTR + sseg + 8] = k1;
                *(us8*)&Vl[srow * PSTR + sseg] = v0; *(us8*)&Vl[srow * PSTR + sseg + 8] = v1;
            }
            __syncthreads();

            // A-frags once per tile, reused by both q-subs
            bf16x8 kfr[4][2], vfr[4][2];
#pragma unroll
            for (int t = 0; t < 4; t++)
#pragma unroll
                for (int ks = 0; ks < 2; ks++) {
                    kfr[t][ks] = *(const bf16x8*)&Kl[(t * 16 + lm) * PSTR + ks * 32 + quad * 8];
                    vfr[t][ks] = *(const bf16x8*)&Vl[(t * 16 + lm) * PSTR + ks * 32 + quad * 8];
                }

#pragma unroll
            for (int q = 0; q < 2; q++) {
                unsigned short* Phq = Ph + (size_t)(w * 2 + q) * 16 * PSTR;
                // S^T: m=key, n=qrow. 2-pass Q hi/lo
                f32x4 s[4];
#pragma unroll
                for (int t = 0; t < 4; t++) s[t] = (f32x4){0.f, 0.f, 0.f, 0.f};
#pragma unroll
                for (int t = 0; t < 4; t++)
#pragma unroll
                    for (int ks = 0; ks < 2; ks++) {
                        s[t] = __builtin_amdgcn_mfma_f32_16x16x32_bf16(kfr[t][ks], qhi[q][ks], s[t], 0, 0, 0);
                        s[t] = __builtin_amdgcn_mfma_f32_16x16x32_bf16(kfr[t][ks], qlo[q][ks], s[t], 0, 0, 0);
                    }
                // p = exp2(s) (log2e folded into Q scale), pack via cvt_pk, per-wave LDS
#pragma unroll
                for (int t = 0; t < 4; t++) {
                    float e0 = exp2f(s[t][0]);
                    float e1 = exp2f(s[t][1]);
                    float e2 = exp2f(s[t][2]);
                    float e3 = exp2f(s[t][3]);
                    rsum[q] += (e0 + e1) + (e2 + e3);
                    unsigned w0 = cvt_pk_bf16(e0, e1);
                    unsigned w1 = cvt_pk_bf16(e2, e3);
                    *(uint2*)&Phq[lm * PSTR + t * 16 + quad * 4] = make_uint2(w0, w1);
                }
                // same-wave write->read ordering via lgkmcnt
                bf16x8 pf0 = *(const bf16x8*)&Phq[lm * PSTR + quad * 8];
                bf16x8 pf1 = *(const bf16x8*)&Phq[lm * PSTR + 32 + quad * 8];
#pragma unroll
                for (int dt = 0; dt < 4; dt++) {
                    o[q][dt] = __builtin_amdgcn_mfma_f32_16x16x32_bf16(vfr[dt][0], pf0, o[q][dt], 0, 0, 0);
                    o[q][dt] = __builtin_amdgcn_mfma_f32_16x16x32_bf16(vfr[dt][1], pf1, o[q][dt], 0, 0, 0);
                }
            }
        }

        // epilogue: bf16 partials + per-qrow denominator partial
#pragma unroll
        for (int q = 0; q < 2; q++) {
            float rs = rsum[q];
            rs += __shfl_xor(rs, 16);
            rs += __shfl_xor(rs, 32);
            int qrow = qt2 * 128 + q * 64 + w * 16 + lm;
            size_t ob = ((size_t)(half * 16 + p) * SEQ + qrow) * 64;
#pragma unroll
            for (int dt = 0; dt < 4; dt++) {
                unsigned w0 = cvt_pk_bf16(o[q][dt][0], o[q][dt][1]);
                unsigned w1 = cvt_pk_bf16(o[q][dt][2], o[q][dt][3]);
                *(uint2*)(OpartUS + ob + dt * 16 + quad * 4) = make_uint2(w0, w1);
            }
            if (quad == 0) lpart[(size_t)(half * 16 + p) * SEQ + qrow] = rs;
        }
    } else {
        // ---------------- gram: MFMA split-4 partials (+ cis precompute on split 0) ----------------
        int split = bid >> 4, p = bid & 15;
        const unsigned short* UhT   = usb + 2 * USZ;
        const unsigned short* EhiT  = usb + 3 * USZ;
        const unsigned short* valsT = usb + 4 * USZ;
        unsigned short* Ut = (unsigned short*)smem;            // 64*40 each
        unsigned short* Eh = Ut + 64 * 40;
        unsigned short* Vt = Eh + 64 * 40;
        f32x4 su[4], sv[4], kv[4];
#pragma unroll
        for (int i = 0; i < 4; i++) { su[i] = (f32x4){0,0,0,0}; sv[i] = (f32x4){0,0,0,0}; kv[i] = (f32x4){0,0,0,0}; }
        int srow = tid >> 2;
        int sseg = (tid & 3) * 8;

        for (int step = 0; step < 16; ++step) {
            int l0 = split * 512 + step * 32;
            __syncthreads();
            size_t gb = ((size_t)p * 64 + srow) * 2048 + l0 + sseg;
            *(us8*)&Ut[srow * 40 + sseg] = *(const us8*)(UhT + gb);
            *(us8*)&Eh[srow * 40 + sseg] = *(const us8*)(EhiT + gb);
            *(us8*)&Vt[srow * 40 + sseg] = *(const us8*)(valsT + gb);
            __syncthreads();
            int ao = (w * 16 + lm) * 40 + quad * 8;
            bf16x8 au  = *(const bf16x8*)&Ut[ao];
            bf16x8 aeh = *(const bf16x8*)&Eh[ao];
#pragma unroll
            for (int nt = 0; nt < 4; nt++) {
                int bo = (nt * 16 + lm) * 40 + quad * 8;
                bf16x8 bu  = *(const bf16x8*)&Ut[bo];
                bf16x8 beh = *(const bf16x8*)&Eh[bo];
                bf16x8 bv  = *(const bf16x8*)&Vt[bo];
                su[nt] = __builtin_amdgcn_mfma_f32_16x16x32_bf16(au,  bu,  su[nt], 0, 0, 0);
                sv[nt] = __builtin_amdgcn_mfma_f32_16x16x32_bf16(aeh, beh, sv[nt], 0, 0, 0);
                kv[nt] = __builtin_amdgcn_mfma_f32_16x16x32_bf16(aeh, bv,  kv[nt], 0, 0, 0);
            }
        }
        float* dst = part + (size_t)(split * 16 + p) * 3 * 4096;
#pragma unroll
        for (int nt = 0; nt < 4; nt++)
#pragma unroll
            for (int reg = 0; reg < 4; reg++) {
                int off = (w * 16 + quad * 4 + reg) * 64 + nt * 16 + lm;
                dst[off] = su[nt][reg];
                dst[4096 + off] = sv[nt][reg];
                dst[8192 + off] = kv[nt][reg];
            }
        if (split == 0) {
            // cis[p][64] = 1 / colsum(E) — computed once here, consumed by all post blocks
            __syncthreads();   // all waves done with Ut/Eh/Vt reads
            float* red = (float*)smem;   // 256 floats
            const float* Spart = part + OFF_SPART;
            int d = tid & 63, grp = tid >> 6;
            float s = 0.0f;
#pragma unroll
            for (int i = 0; i < 8; i++) s += Spart[(p * 32 + grp * 8 + i) * 64 + d];
            red[grp * 64 + d] = s;
            __syncthreads();
            if (tid < 64)
                part[OFF_CIS + p * 64 + tid] =
                    1.0f / (red[tid] + red[64 + tid] + red[128 + tid] + red[192 + tid]);
        }
    }
}

// ================= post: agf+smerge (0..511) + ortho x4 (512..575) =================
__global__ __launch_bounds__(256) void post(const float* __restrict__ part, const float* __restrict__ Spart,
                                            const unsigned short* __restrict__ usb,
                                            const unsigned short* __restrict__ OpartUS,
                                            const float* __restrict__ lpart, float* __restrict__ out) {
    (void)Spart;
    const int bid = blockIdx.x;
    const int tid = threadIdx.x;
    const int w = tid >> 6, lane = tid & 63, lm = lane & 15, quad = lane >> 4;
    int p = (bid < 512) ? (bid >> 5) : ((bid - 512) >> 2);
    __shared__ float cisl[64];
    __shared__ float redo[4];
    __shared__ __align__(16) unsigned short KVh[64 * PSTR];
    __shared__ __align__(16) unsigned short KVl[64 * PSTR];
    if (tid < 64) cisl[tid] = part[OFF_CIS + p * 64 + tid];
    __syncthreads();
    if (bid >= 512) {
        // ---- ortho loss for pair p, i-chunk (4 chunks per p) ----
        int chunk = (bid - 512) & 3;
        float s = 0.0f;
        for (int t = 0; t < 8; t++) {
            int idx = chunk * 2048 + t * 256 + tid;
            int g = idx >> 12, i = idx & 4095;
            float v = 0.0f;
#pragma unroll
            for (int sp = 0; sp < 4; sp++) v += part[((size_t)(sp * 16 + p) * 3 + g) * 4096 + i];
            if (g) v *= cisl[i >> 6] * cisl[i & 63];
            float dg = ((i >> 6) == (i & 63)) ? 1.0f : 0.0f;
            s += fabsf(v - dg);
        }
#pragma unroll
        for (int o = 32; o > 0; o >>= 1) s += __shfl_xor(s, o);
        if (lane == 0) redo[w] = s;
        __syncthreads();
        if (tid == 0)
            atomicAdd(&out[LOSS_BASE + (p >> 2)],
                      (redo[0] + redo[1] + redo[2] + redo[3]) * (1.0f / 16384.0f));
        return;
    }
    // ---- agf block (p, lt): fused smerge for its 64 rows, then Ug @ KV ----
    int lt = bid & 31;
    int b = p >> 2, h = p & 3;
    {
        // smerge: combine 2 split-K halves for rows lt*64 .. lt*64+63, write softmax heads
        int r = tid >> 2, c0 = (tid & 3) * 16;
        int l = lt * 64 + r;
        size_t o0 = ((size_t)p * SEQ + l) * 64 + c0;
        size_t o1 = ((size_t)(16 + p) * SEQ + l) * 64 + c0;
        us8 a0 = *(const us8*)(OpartUS + o0);
        us8 a1 = *(const us8*)(OpartUS + o0 + 8);
        us8 d0 = *(const us8*)(OpartUS + o1);
        us8 d1 = *(const us8*)(OpartUS + o1 + 8);
        float inv = 1.0f / (lpart[(size_t)p * SEQ + l] + lpart[(size_t)(16 + p) * SEQ + l]);
        float* ob = out + ((size_t)(b * SEQ + l) * HOUT + 4 + h) * D + c0;
        f32x4 r0, r1, r2, r3;
#pragma unroll
        for (int j = 0; j < 4; j++) {
            r0[j] = (bf2f(a0[j]) + bf2f(d0[j])) * inv;
            r1[j] = (bf2f(a0[4 + j]) + bf2f(d0[4 + j])) * inv;
            r2[j] = (bf2f(a1[j]) + bf2f(d1[j])) * inv;
            r3[j] = (bf2f(a1[4 + j]) + bf2f(d1[4 + j])) * inv;
        }
        *(f32x4*)ob = r0; *(f32x4*)(ob + 4) = r1;
        *(f32x4*)(ob + 8) = r2; *(f32x4*)(ob + 12) = r3;
    }
    const unsigned short* Ughi = usb + 5 * USZ;
    const unsigned short* Uglo = usb + 6 * USZ;
    for (int idx = tid; idx < 4096; idx += 256) {
        int d = idx >> 6, e = idx & 63;
        float v = 0.0f;
#pragma unroll
        for (int sp = 0; sp < 4; sp++) v += part[((size_t)(sp * 16 + p) * 3 + 2) * 4096 + idx];
        v *= cisl[d];
        unsigned short hh = f2bf(v);
        KVh[e * PSTR + d] = hh;
        KVl[e * PSTR + d] = f2bf(v - bf2f(hh));
    }
    __syncthreads();
    size_t ub = ((size_t)(p * SEQ + lt * 64 + w * 16 + lm)) * 64 + quad * 8;
    bf16x8 ah[2], al[2];
#pragma unroll
    for (int ks = 0; ks < 2; ks++) {
        ah[ks] = *(const bf16x8*)(Ughi + ub + ks * 32);
        al[ks] = *(const bf16x8*)(Uglo + ub + ks * 32);
    }
    f32x4 acc[4];
#pragma unroll
    for (int nt = 0; nt < 4; nt++) acc[nt] = (f32x4){0.f, 0.f, 0.f, 0.f};
#pragma unroll
    for (int nt = 0; nt < 4; nt++)
#pragma unroll
        for (int ks = 0; ks < 2; ks++) {
            bf16x8 bh = *(const bf16x8*)&KVh[(nt * 16 + lm) * PSTR + ks * 32 + quad * 8];
            bf16x8 bl = *(const bf16x8*)&KVl[(nt * 16 + lm) * PSTR + ks * 32 + quad * 8];
            acc[nt] = __builtin_amdgcn_mfma_f32_16x16x32_bf16(ah[ks], bh, acc[nt], 0, 0, 0);
            acc[nt] = __builtin_amdgcn_mfma_f32_16x16x32_bf16(al[ks], bh, acc[nt], 0, 0, 0);
            acc[nt] = __builtin_amdgcn_mfma_f32_16x16x32_bf16(ah[ks], bl, acc[nt], 0, 0, 0);
        }
#pragma unroll
    for (int nt = 0; nt < 4; nt++)
#pragma unroll
        for (int reg = 0; reg < 4; reg++)
            out[((size_t)(b * SEQ + lt * 64 + w * 16 + quad * 4 + reg) * HOUT + h) * D + nt * 16 + lm] =
                acc[nt][reg];
}

extern "C" void kernel_launch(void* const* d_in, const int* in_sizes, int n_in,
                              void* d_out, int out_size, void* d_ws, size_t ws_size,
                              hipStream_t stream) {
    (void)in_sizes; (void)n_in; (void)out_size; (void)ws_size;
    const float* U    = (const float*)d_in[0];
    const float* Sg   = (const float*)d_in[1];
    const float* V    = (const float*)d_in[2];
    const float* vals = (const float*)d_in[3];
    const float* Qs   = (const float*)d_in[4];
    const float* Ks   = (const float*)d_in[5];
    const float* Vv   = (const float*)d_in[6];
    const float* gam  = (const float*)d_in[7];
    float* out = (float*)d_out;

    float* ws = (float*)d_ws;
    float* part  = ws;
    float* Spart = ws + OFF_SPART;
    float* lpart = ws + OFF_LPART;
    unsigned short* usb = (unsigned short*)(ws + OFF_F32_END);
    unsigned short* OpartUS = usb + 7 * USZ;

    prep<<<dim3(32, 16, 5), 256, 0, stream>>>(U, Sg, V, vals, Ks, Vv, gam, ws, usb, out);
    mid<<<576, 256, 0, stream>>>(usb, Qs, part, OpartUS, lpart);
    post<<<576, 256, 0, stream>>>(part, Spart, usb, OpartUS, lpart, out);
}

// Round 10
// 161.153 us; speedup vs baseline: 1.5175x; 1.0131x over previous
//
#include <hip/hip_runtime.h>
#include <hip/hip_bf16.h>

#define BB 4
#define SEQ 2048
#define NH 4
#define D 64
#define NPAIR 16
#define HOUT 8
#define LOSS_BASE ((size_t)BB * SEQ * HOUT * D)

// ---- ws layout ----
// f32: part[4][16][3][4096] | Spart[16][32][64] | lpart[2][16][2048]
// ushort: usb: 0 Khi, 1 VbfT, 2 UhT, 3 EhiT, 4 valsT, 5 Ughi, 6 Uglo  (each 16*2048*64)
// ushort: OpartUS[2][16][2048][64]
#define N_PART   (4 * 16 * 3 * 4096)
#define OFF_SPART N_PART
#define N_SPART  (16 * 32 * 64)
#define OFF_LPART (OFF_SPART + N_SPART)
#define N_LPART  (2 * 16 * 2048)
#define OFF_F32_END (OFF_LPART + N_LPART)
#define USZ ((size_t)16 * 2048 * 64)

typedef __attribute__((ext_vector_type(8))) short bf16x8;
typedef __attribute__((ext_vector_type(4))) float f32x4;
typedef __attribute__((ext_vector_type(8))) unsigned short us8;
typedef __attribute__((ext_vector_type(4))) unsigned short us4;

__device__ __forceinline__ unsigned short f2bf(float x) {
    union { float f; unsigned u; } v; v.f = x;
    unsigned r = v.u + 0x7fffu + ((v.u >> 16) & 1u);
    return (unsigned short)(r >> 16);
}
__device__ __forceinline__ float bf2f(unsigned short u) {
    union { unsigned u; float f; } v; v.u = ((unsigned)u) << 16; return v.f;
}
// packed RNE f32->bf16 pair: dst = bf16(lo) | bf16(hi)<<16  (bit-identical to f2bf)
__device__ __forceinline__ unsigned cvt_pk_bf16(float lo, float hi) {
    unsigned r;
    asm("v_cvt_pk_bf16_f32 %0, %1, %2" : "=v"(r) : "v"(lo), "v"(hi));
    return r;
}
__device__ __forceinline__ void load16(const float* p, float* v) {
    const float4* q = (const float4*)p;
    float4 a = q[0], b = q[1], c = q[2], d = q[3];
    v[0]=a.x; v[1]=a.y; v[2]=a.z; v[3]=a.w;
    v[4]=b.x; v[5]=b.y; v[6]=b.z; v[7]=b.w;
    v[8]=c.x; v[9]=c.y; v[10]=c.z; v[11]=c.w;
    v[12]=d.x; v[13]=d.y; v[14]=d.z; v[15]=d.w;
}
__device__ __forceinline__ void wr_bf16x16(unsigned short* dst, const float* v) {
    unsigned w[8];
#pragma unroll
    for (int i = 0; i < 8; i++) w[i] = cvt_pk_bf16(v[2 * i], v[2 * i + 1]);
    *(uint4*)dst = make_uint4(w[0], w[1], w[2], w[3]);
    *(uint4*)(dst + 8) = make_uint4(w[4], w[5], w[6], w[7]);
}

// ================= prep: stage-parallel conversions (z = stage) =================
__global__ __launch_bounds__(256) void prep(const float* __restrict__ U, const float* __restrict__ Sg,
                                            const float* __restrict__ Vagf, const float* __restrict__ vals,
                                            const float* __restrict__ Ksm, const float* __restrict__ Vsm,
                                            const float* __restrict__ gam,
                                            float* __restrict__ ws, unsigned short* __restrict__ usb,
                                            float* __restrict__ out) {
    int lt = blockIdx.x, p = blockIdx.y, stage = blockIdx.z;
    int b = p >> 2, h = p & 3;
    int tid = threadIdx.x;
    int r = tid >> 2;
    int c0 = (tid & 3) * 16;
    __shared__ float T[64][69];   // 69: col-read stride 69%32=5, c0 groups 16*69%32=16 -> 2-way (free)
    unsigned short* Khi   = usb;
    unsigned short* VbfT  = usb + USZ;
    unsigned short* UhT   = usb + 2 * USZ;
    unsigned short* EhiT  = usb + 3 * USZ;
    unsigned short* valsT = usb + 4 * USZ;
    unsigned short* Ughi  = usb + 5 * USZ;
    unsigned short* Uglo  = usb + 6 * USZ;
    float* Spart = ws + OFF_SPART;

    const size_t gbase = ((size_t)(b * SEQ + lt * 64 + r) * NH + h) * D + c0;
    const size_t nbase = ((size_t)(p * SEQ + lt * 64 + r)) * 64 + c0;      // [p][l][d]
    const size_t tbase = ((size_t)p * 64 + r) * 2048 + lt * 64 + c0;      // [p][d][l]
    float v[16], e[16];

    if (stage == 0) {
        // U -> row softmax -> Ug (natural hi/lo) + UhT (transposed bf16)
        load16(U + gbase, v);
        float mx = v[0];
#pragma unroll
        for (int k = 1; k < 16; k++) mx = fmaxf(mx, v[k]);
        mx = fmaxf(mx, __shfl_xor(mx, 1));
        mx = fmaxf(mx, __shfl_xor(mx, 2));
        float sm = 0.0f;
#pragma unroll
        for (int k = 0; k < 16; k++) { v[k] = __expf(v[k] - mx); sm += v[k]; }
        sm += __shfl_xor(sm, 1);
        sm += __shfl_xor(sm, 2);
        float inv = 1.0f / sm;
#pragma unroll
        for (int k = 0; k < 16; k++) { v[k] *= inv; T[r][c0 + k] = v[k]; }
        float sg[16];
        load16(Sg + gbase, sg);
        float g0 = gam[0], g1 = gam[1], g2 = gam[2], g3 = gam[3];
        us8 h0, h1, l0, l1;
#pragma unroll
        for (int k = 0; k < 16; k++) {
            float sig = 1.0f / (1.0f + __expf(-sg[k]));
            float x1 = 2.0f * sig;
            float x2 = 1.875f * sig * x1 - 0.75f;
            float x3 = 1.8666666666666667f * sig * x2 - 0.8f * x1;
            float ug = v[k] * (g0 + g1 * x1 + g2 * x2 + g3 * x3);
            unsigned short hh = f2bf(ug);
            unsigned short ll = f2bf(ug - bf2f(hh));
            if (k < 8) { h0[k] = hh; l0[k] = ll; } else { h1[k - 8] = hh; l1[k - 8] = ll; }
        }
        *(us8*)(Ughi + nbase) = h0; *(us8*)(Ughi + nbase + 8) = h1;
        *(us8*)(Uglo + nbase) = l0; *(us8*)(Uglo + nbase + 8) = l1;
        __syncthreads();
#pragma unroll
        for (int k = 0; k < 16; k++) e[k] = T[c0 + k][r];
        wr_bf16x16(UhT + tbase, e);
    } else if (stage == 1) {
        // E = exp(Vagf) -> EhiT + column sums
        load16(Vagf + gbase, v);
#pragma unroll
        for (int k = 0; k < 16; k++) T[r][c0 + k] = __expf(v[k]);
        __syncthreads();
        float ssum = 0.0f;
#pragma unroll
        for (int k = 0; k < 16; k++) { e[k] = T[c0 + k][r]; ssum += e[k]; }
        ssum += __shfl_xor(ssum, 1);
        ssum += __shfl_xor(ssum, 2);
        if ((tid & 3) == 0) Spart[(p * 32 + lt) * 64 + r] = ssum;
        wr_bf16x16(EhiT + tbase, e);
    } else if (stage == 2) {
        load16(vals + gbase, v);
#pragma unroll
        for (int k = 0; k < 16; k++) T[r][c0 + k] = v[k];
        __syncthreads();
#pragma unroll
        for (int k = 0; k < 16; k++) e[k] = T[c0 + k][r];
        wr_bf16x16(valsT + tbase, e);
    } else if (stage == 3) {
        load16(Vsm + gbase, v);
#pragma unroll
        for (int k = 0; k < 16; k++) T[r][c0 + k] = v[k];
        __syncthreads();
#pragma unroll
        for (int k = 0; k < 16; k++) e[k] = T[c0 + k][r];
        wr_bf16x16(VbfT + tbase, e);
    } else {
        load16(Ksm + gbase, v);
        wr_bf16x16(Khi + nbase, v);
        if (lt == 0 && p == 0 && tid < BB) out[LOSS_BASE + tid] = 0.0f;
    }
}

// ================= mid: gram (0..63) + flash (64..575, split-K x2 — R4 config) =================
#define PSTR 72
// Q scale: 1/sqrt(64) * log2(e), so exp2(S) == exp(S/8)
#define QSC 0.18033688011112042f

__global__ __launch_bounds__(256, 2) void mid(const unsigned short* __restrict__ usb,
                                              const float* __restrict__ Q,
                                              float* __restrict__ part,
                                              unsigned short* __restrict__ OpartUS,
                                              float* __restrict__ lpart) {
    __shared__ __align__(16) unsigned char smem[36864];
    const int bid = blockIdx.x;
    const int tid = threadIdx.x;
    const int w = tid >> 6, lane = tid & 63, lm = lane & 15, quad = lane >> 4;

    if (bid >= 64) {
        // ---------------- flash: 128 qrows/block, LDS K/V, reg-cached A-frags, split-K x2 ----------------
        int fb = bid - 64;
        int qt2 = fb & 15, p = (fb >> 4) & 15, half = fb >> 8;
        int b = p >> 2, h = p & 3;
        const unsigned short* Khi  = usb;
        const unsigned short* VbfT = usb + USZ;
        unsigned short* Kl = (unsigned short*)smem;                        // [64][PSTR]
        unsigned short* Vl = Kl + 64 * PSTR;                               // [64][PSTR] (rows=d)
        unsigned short* Ph = Vl + 64 * PSTR;                               // [4w][2q][16][PSTR]
        const int srow = tid >> 2, sseg = (tid & 3) * 16;

        // Q B-frags for 2 q-subs: B[n=lm][k=quad*8+j], scale QSC, hi/lo
        bf16x8 qhi[2][2], qlo[2][2];
#pragma unroll
        for (int q = 0; q < 2; q++) {
            int row = qt2 * 128 + q * 64 + w * 16 + lm;
            const float* qp = Q + ((size_t)(b * SEQ + row) * NH + h) * D + quad * 8;
#pragma unroll
            for (int ks = 0; ks < 2; ks++) {
                float qq[8];
                float4 a0 = *(const float4*)(qp + ks * 32);
                float4 a1 = *(const float4*)(qp + ks * 32 + 4);
                qq[0]=a0.x; qq[1]=a0.y; qq[2]=a0.z; qq[3]=a0.w;
                qq[4]=a1.x; qq[5]=a1.y; qq[6]=a1.z; qq[7]=a1.w;
#pragma unroll
                for (int j = 0; j < 8; j++) {
                    float xs = qq[j] * QSC;
                    unsigned short hi = f2bf(xs);
                    qhi[q][ks][j] = (short)hi;
                    qlo[q][ks][j] = (short)f2bf(xs - bf2f(hi));
                }
            }
        }

        float rsum[2] = {0.f, 0.f};
        f32x4 o[2][4];
#pragma unroll
        for (int q = 0; q < 2; q++)
#pragma unroll
            for (int t = 0; t < 4; t++) o[q][t] = (f32x4){0.f, 0.f, 0.f, 0.f};

        for (int kt = 0; kt < 16; ++kt) {
            __syncthreads();
            {   // stage K [key][d] and V^T [d][key]
                size_t kb = ((size_t)(p * SEQ + half * 1024 + kt * 64 + srow)) * 64 + sseg;
                us8 k0 = *(const us8*)(Khi + kb);
                us8 k1 = *(const us8*)(Khi + kb + 8);
                size_t vb = ((size_t)p * 64 + srow) * 2048 + half * 1024 + kt * 64 + sseg;
                us8 v0 = *(const us8*)(VbfT + vb);
                us8 v1 = *(const us8*)(VbfT + vb + 8);
                *(us8*)&Kl[srow * PSTR + sseg] = k0; *(us8*)&Kl[srow * PSTR + sseg + 8] = k1;
                *(us8*)&Vl[srow * PSTR + sseg] = v0; *(us8*)&Vl[srow * PSTR + sseg + 8] = v1;
            }
            __syncthreads();

            // A-frags once per tile, reused by both q-subs
            bf16x8 kfr[4][2], vfr[4][2];
#pragma unroll
            for (int t = 0; t < 4; t++)
#pragma unroll
                for (int ks = 0; ks < 2; ks++) {
                    kfr[t][ks] = *(const bf16x8*)&Kl[(t * 16 + lm) * PSTR + ks * 32 + quad * 8];
                    vfr[t][ks] = *(const bf16x8*)&Vl[(t * 16 + lm) * PSTR + ks * 32 + quad * 8];
                }

#pragma unroll
            for (int q = 0; q < 2; q++) {
                unsigned short* Phq = Ph + (size_t)(w * 2 + q) * 16 * PSTR;
                // S^T: m=key, n=qrow. 2-pass Q hi/lo
                f32x4 s[4];
#pragma unroll
                for (int t = 0; t < 4; t++) s[t] = (f32x4){0.f, 0.f, 0.f, 0.f};
#pragma unroll
                for (int t = 0; t < 4; t++)
#pragma unroll
                    for (int ks = 0; ks < 2; ks++) {
                        s[t] = __builtin_amdgcn_mfma_f32_16x16x32_bf16(kfr[t][ks], qhi[q][ks], s[t], 0, 0, 0);
                        s[t] = __builtin_amdgcn_mfma_f32_16x16x32_bf16(kfr[t][ks], qlo[q][ks], s[t], 0, 0, 0);
                    }
                // p = exp2(s) (log2e folded into Q scale), pack via cvt_pk, per-wave LDS
#pragma unroll
                for (int t = 0; t < 4; t++) {
                    float e0 = exp2f(s[t][0]);
                    float e1 = exp2f(s[t][1]);
                    float e2 = exp2f(s[t][2]);
                    float e3 = exp2f(s[t][3]);
                    rsum[q] += (e0 + e1) + (e2 + e3);
                    unsigned w0 = cvt_pk_bf16(e0, e1);
                    unsigned w1 = cvt_pk_bf16(e2, e3);
                    *(uint2*)&Phq[lm * PSTR + t * 16 + quad * 4] = make_uint2(w0, w1);
                }
                // same-wave write->read ordering via lgkmcnt
                bf16x8 pf0 = *(const bf16x8*)&Phq[lm * PSTR + quad * 8];
                bf16x8 pf1 = *(const bf16x8*)&Phq[lm * PSTR + 32 + quad * 8];
#pragma unroll
                for (int dt = 0; dt < 4; dt++) {
                    o[q][dt] = __builtin_amdgcn_mfma_f32_16x16x32_bf16(vfr[dt][0], pf0, o[q][dt], 0, 0, 0);
                    o[q][dt] = __builtin_amdgcn_mfma_f32_16x16x32_bf16(vfr[dt][1], pf1, o[q][dt], 0, 0, 0);
                }
            }
        }

        // epilogue: bf16 partials + per-qrow denominator partial
#pragma unroll
        for (int q = 0; q < 2; q++) {
            float rs = rsum[q];
            rs += __shfl_xor(rs, 16);
            rs += __shfl_xor(rs, 32);
            int qrow = qt2 * 128 + q * 64 + w * 16 + lm;
            size_t ob = ((size_t)(half * 16 + p) * SEQ + qrow) * 64;
#pragma unroll
            for (int dt = 0; dt < 4; dt++) {
                unsigned w0 = cvt_pk_bf16(o[q][dt][0], o[q][dt][1]);
                unsigned w1 = cvt_pk_bf16(o[q][dt][2], o[q][dt][3]);
                *(uint2*)(OpartUS + ob + dt * 16 + quad * 4) = make_uint2(w0, w1);
            }
            if (quad == 0) lpart[(size_t)(half * 16 + p) * SEQ + qrow] = rs;
        }
    } else {
        // ---------------- gram: MFMA split-4 partials ----------------
        int split = bid >> 4, p = bid & 15;
        const unsigned short* UhT   = usb + 2 * USZ;
        const unsigned short* EhiT  = usb + 3 * USZ;
        const unsigned short* valsT = usb + 4 * USZ;
        unsigned short* Ut = (unsigned short*)smem;            // 64*40 each
        unsigned short* Eh = Ut + 64 * 40;
        unsigned short* Vt = Eh + 64 * 40;
        f32x4 su[4], sv[4], kv[4];
#pragma unroll
        for (int i = 0; i < 4; i++) { su[i] = (f32x4){0,0,0,0}; sv[i] = (f32x4){0,0,0,0}; kv[i] = (f32x4){0,0,0,0}; }
        int srow = tid >> 2;
        int sseg = (tid & 3) * 8;

        for (int step = 0; step < 16; ++step) {
            int l0 = split * 512 + step * 32;
            __syncthreads();
            size_t gb = ((size_t)p * 64 + srow) * 2048 + l0 + sseg;
            *(us8*)&Ut[srow * 40 + sseg] = *(const us8*)(UhT + gb);
            *(us8*)&Eh[srow * 40 + sseg] = *(const us8*)(EhiT + gb);
            *(us8*)&Vt[srow * 40 + sseg] = *(const us8*)(valsT + gb);
            __syncthreads();
            int ao = (w * 16 + lm) * 40 + quad * 8;
            bf16x8 au  = *(const bf16x8*)&Ut[ao];
            bf16x8 aeh = *(const bf16x8*)&Eh[ao];
#pragma unroll
            for (int nt = 0; nt < 4; nt++) {
                int bo = (nt * 16 + lm) * 40 + quad * 8;
                bf16x8 bu  = *(const bf16x8*)&Ut[bo];
                bf16x8 beh = *(const bf16x8*)&Eh[bo];
                bf16x8 bv  = *(const bf16x8*)&Vt[bo];
                su[nt] = __builtin_amdgcn_mfma_f32_16x16x32_bf16(au,  bu,  su[nt], 0, 0, 0);
                sv[nt] = __builtin_amdgcn_mfma_f32_16x16x32_bf16(aeh, beh, sv[nt], 0, 0, 0);
                kv[nt] = __builtin_amdgcn_mfma_f32_16x16x32_bf16(aeh, bv,  kv[nt], 0, 0, 0);
            }
        }
        float* dst = part + (size_t)(split * 16 + p) * 3 * 4096;
#pragma unroll
        for (int nt = 0; nt < 4; nt++)
#pragma unroll
            for (int reg = 0; reg < 4; reg++) {
                int off = (w * 16 + quad * 4 + reg) * 64 + nt * 16 + lm;
                dst[off] = su[nt][reg];
                dst[4096 + off] = sv[nt][reg];
                dst[8192 + off] = kv[nt][reg];
            }
    }
}

// ================= post: agf+smerge (0..511) + ortho x4 (512..575) =================
__global__ __launch_bounds__(256) void post(const float* __restrict__ part, const float* __restrict__ Spart,
                                            const unsigned short* __restrict__ usb,
                                            const unsigned short* __restrict__ OpartUS,
                                            const float* __restrict__ lpart, float* __restrict__ out) {
    const int bid = blockIdx.x;
    const int tid = threadIdx.x;
    const int w = tid >> 6, lane = tid & 63, lm = lane & 15, quad = lane >> 4;
    int p = (bid < 512) ? (bid >> 5) : ((bid - 512) >> 2);
    __shared__ float cis[64];
    __shared__ float red[4][64];
    __shared__ __align__(16) unsigned short KVh[64 * PSTR];
    __shared__ __align__(16) unsigned short KVl[64 * PSTR];
    {
        int d = tid & 63, grp = tid >> 6;
        float s = 0.0f;
#pragma unroll
        for (int i = 0; i < 8; i++) s += Spart[(p * 32 + grp * 8 + i) * 64 + d];
        red[grp][d] = s;
        __syncthreads();
        if (tid < 64) cis[tid] = 1.0f / (red[0][tid] + red[1][tid] + red[2][tid] + red[3][tid]);
        __syncthreads();
    }
    if (bid >= 512) {
        // ---- ortho loss for pair p, i-chunk (4 chunks per p) ----
        int chunk = (bid - 512) & 3;
        float s = 0.0f;
        for (int t = 0; t < 8; t++) {
            int idx = chunk * 2048 + t * 256 + tid;
            int g = idx >> 12, i = idx & 4095;
            float v = 0.0f;
#pragma unroll
            for (int sp = 0; sp < 4; sp++) v += part[((size_t)(sp * 16 + p) * 3 + g) * 4096 + i];
            if (g) v *= cis[i >> 6] * cis[i & 63];
            float dg = ((i >> 6) == (i & 63)) ? 1.0f : 0.0f;
            s += fabsf(v - dg);
        }
#pragma unroll
        for (int o = 32; o > 0; o >>= 1) s += __shfl_xor(s, o);
        if (lane == 0) red[0][w * 2] = s;
        __syncthreads();
        if (tid == 0)
            atomicAdd(&out[LOSS_BASE + (p >> 2)],
                      (red[0][0] + red[0][2] + red[0][4] + red[0][6]) * (1.0f / 16384.0f));
        return;
    }
    // ---- agf block (p, lt): fused smerge for its 64 rows, then Ug @ KV ----
    int lt = bid & 31;
    int b = p >> 2, h = p & 3;
    {
        // smerge: combine 2 split-K halves for rows lt*64 .. lt*64+63, write softmax heads
        int r = tid >> 2, c0 = (tid & 3) * 16;
        int l = lt * 64 + r;
        size_t o0 = ((size_t)p * SEQ + l) * 64 + c0;
        size_t o1 = ((size_t)(16 + p) * SEQ + l) * 64 + c0;
        us8 a0 = *(const us8*)(OpartUS + o0);
        us8 a1 = *(const us8*)(OpartUS + o0 + 8);
        us8 d0 = *(const us8*)(OpartUS + o1);
        us8 d1 = *(const us8*)(OpartUS + o1 + 8);
        float inv = 1.0f / (lpart[(size_t)p * SEQ + l] + lpart[(size_t)(16 + p) * SEQ + l]);
        float* ob = out + ((size_t)(b * SEQ + l) * HOUT + 4 + h) * D + c0;
        f32x4 r0, r1, r2, r3;
#pragma unroll
        for (int j = 0; j < 4; j++) {
            r0[j] = (bf2f(a0[j]) + bf2f(d0[j])) * inv;
            r1[j] = (bf2f(a0[4 + j]) + bf2f(d0[4 + j])) * inv;
            r2[j] = (bf2f(a1[j]) + bf2f(d1[j])) * inv;
            r3[j] = (bf2f(a1[4 + j]) + bf2f(d1[4 + j])) * inv;
        }
        *(f32x4*)ob = r0; *(f32x4*)(ob + 4) = r1;
        *(f32x4*)(ob + 8) = r2; *(f32x4*)(ob + 12) = r3;
    }
    const unsigned short* Ughi = usb + 5 * USZ;
    const unsigned short* Uglo = usb + 6 * USZ;
    for (int idx = tid; idx < 4096; idx += 256) {
        int d = idx >> 6, e = idx & 63;
        float v = 0.0f;
#pragma unroll
        for (int sp = 0; sp < 4; sp++) v += part[((size_t)(sp * 16 + p) * 3 + 2) * 4096 + idx];
        v *= cis[d];
        unsigned short hh = f2bf(v);
        KVh[e * PSTR + d] = hh;
        KVl[e * PSTR + d] = f2bf(v - bf2f(hh));
    }
    __syncthreads();
    size_t ub = ((size_t)(p * SEQ + lt * 64 + w * 16 + lm)) * 64 + quad * 8;
    bf16x8 ah[2], al[2];
#pragma unroll
    for (int ks = 0; ks < 2; ks++) {
        ah[ks] = *(const bf16x8*)(Ughi + ub + ks * 32);
        al[ks] = *(const bf16x8*)(Uglo + ub + ks * 32);
    }
    f32x4 acc[4];
#pragma unroll
    for (int nt = 0; nt < 4; nt++) acc[nt] = (f32x4){0.f, 0.f, 0.f, 0.f};
#pragma unroll
    for (int nt = 0; nt < 4; nt++)
#pragma unroll
        for (int ks = 0; ks < 2; ks++) {
            bf16x8 bh = *(const bf16x8*)&KVh[(nt * 16 + lm) * PSTR + ks * 32 + quad * 8];
            bf16x8 bl = *(const bf16x8*)&KVl[(nt * 16 + lm) * PSTR + ks * 32 + quad * 8];
            acc[nt] = __builtin_amdgcn_mfma_f32_16x16x32_bf16(ah[ks], bh, acc[nt], 0, 0, 0);
            acc[nt] = __builtin_amdgcn_mfma_f32_16x16x32_bf16(al[ks], bh, acc[nt], 0, 0, 0);
            acc[nt] = __builtin_amdgcn_mfma_f32_16x16x32_bf16(ah[ks], bl, acc[nt], 0, 0, 0);
        }
#pragma unroll
    for (int nt = 0; nt < 4; nt++)
#pragma unroll
        for (int reg = 0; reg < 4; reg++)
            out[((size_t)(b * SEQ + lt * 64 + w * 16 + quad * 4 + reg) * HOUT + h) * D + nt * 16 + lm] =
                acc[nt][reg];
}

extern "C" void kernel_launch(void* const* d_in, const int* in_sizes, int n_in,
                              void* d_out, int out_size, void* d_ws, size_t ws_size,
                              hipStream_t stream) {
    (void)in_sizes; (void)n_in; (void)out_size; (void)ws_size;
    const float* U    = (const float*)d_in[0];
    const float* Sg   = (const float*)d_in[1];
    const float* V    = (const float*)d_in[2];
    const float* vals = (const float*)d_in[3];
    const float* Qs   = (const float*)d_in[4];
    const float* Ks   = (const float*)d_in[5];
    const float* Vv   = (const float*)d_in[6];
    const float* gam  = (const float*)d_in[7];
    float* out = (float*)d_out;

    float* ws = (float*)d_ws;
    float* part  = ws;
    float* Spart = ws + OFF_SPART;
    float* lpart = ws + OFF_LPART;
    unsigned short* usb = (unsigned short*)(ws + OFF_F32_END);
    unsigned short* OpartUS = usb + 7 * USZ;

    prep<<<dim3(32, 16, 5), 256, 0, stream>>>(U, Sg, V, vals, Ks, Vv, gam, ws, usb, out);
    mid<<<576, 256, 0, stream>>>(usb, Qs, part, OpartUS, lpart);
    post<<<576, 256, 0, stream>>>(part, Spart, usb, OpartUS, lpart, out);
}